// Round 6
// baseline (647.955 us; speedup 1.0000x reference)
//
#include <hip/hip_runtime.h>
#include <math.h>

// ===================== R12: DIAGNOSTIC ROUND =====================
// Five structurally disjoint kernels (R6,R8,R9,R10,R11) all run at
// ~143-175 us vs the 67 us write roofline demonstrated by the harness's
// own poison fill (1.669 GB @ 6.26 TB/s, FETCH~0). Every intra-kernel
// theory is falsified. Crucially, our dispatch's OWN counters have never
// been observed: the top-5 table is filled by the ~270 us fills and our
// ~150 us dispatch sits below the cutoff.
//
// This round: R8's known-good persistent kernel, sweeping the full output
// REPS=4 times (recompute + re-store identical values; passes separated
// by ~150 us >> L2 residence ~11 us, so each pass drains to HBM).
// Byte-scaling discriminator + guaranteed top-5 visibility:
//   World M (per-byte ~2.9 TB/s): ours ~580 us, WRITE~1.67 GB; FETCH is
//     the tell: ~0 -> true marginal-rate deficit; ~1.6 GB -> write-
//     allocate reads were real all along (R6 analogy-falsification wrong).
//   World F (fixed ~76 us overhead): ours ~344 us, WRITE~1.67 GB @ 4.8 TB/s.
//   World L (bytes don't scale): ours invisible, total ~420 us.
// =================================================================

#define ROWS 32
#define SEG  25     // bins per segment; 8 segments, last has 24
#define NB   199
#define NT   256
#define GRID 1536   // 256 CU x 6 blocks/CU
#define REPS 4      // diagnostic byte multiplier

typedef float fx4 __attribute__((ext_vector_type(4)));

__device__ __forceinline__ void sync_lds_only() {
    asm volatile("s_waitcnt lgkmcnt(0)" ::: "memory");
    __builtin_amdgcn_s_barrier();
    __builtin_amdgcn_sched_barrier(0);
}

__global__ __launch_bounds__(NT, 6)
void gauss_cdf_kernel(const float2* __restrict__ x, float* __restrict__ out, int B) {
    __shared__ __align__(16) float lds[ROWS * NB];   // 25,472 B, flat == out layout
    __shared__ float tot[8 * ROWS];                  // per-segment totals [seg][row]

    const int tid = threadIdx.x;
    const int r   = tid & 31;        // row within group
    const int q   = tid >> 5;        // segment index 0..7
    const int nG  = (B + ROWS - 1) / ROWS;   // 16384 row-groups

    const int qs   = q * SEG;
    const int qlen = (q == 7) ? 24 : 25;     // bin 199 doesn't exist

    for (int rep = 0; rep < REPS; ++rep) {
        int g = blockIdx.x;
        float2 v = make_float2(0.f, 0.f);
        if (g < nG) {                            // prologue load for first group
            int row = g * ROWS + r;
            v = x[row < B ? row : 0];
        }

        for (; g < nG; g += GRID) {
            const int rowBase = g * ROWS;

            const float mu = v.x;
            const float s  = __expf(-0.5f * v.y);            // 1/sigma
            const float inv_norm = 0.3989422804014327f * s;  // 1/(sigma*sqrt(2pi))
            const float coefA2   = -0.7213475204444817f * s * s; // -log2e/(2 s^2)

            const float tb = (float)(qs - 99) - mu;

            // segment cumsum in registers (fully unrolled -> static indices)
            float c[SEG];
            float acc = 0.f;
            #pragma unroll
            for (int j = 0; j < SEG; ++j) {
                float t = tb + (float)j;
                acc += inv_norm * __builtin_amdgcn_exp2f(coefA2 * t * t);
                c[j] = acc;
            }
            tot[q * ROWS + r] = acc;   // q=7's extra bin harmless: tot[7] never read
            sync_lds_only();           // barrier 1

            // prefix of earlier segments' totals
            float base = 0.f;
            #pragma unroll
            for (int k = 0; k < 7; ++k)
                if (k < q) base += tot[k * ROWS + r];

            float* dst = lds + r * NB + qs;
            #pragma unroll
            for (int j = 0; j < SEG; ++j)
                if (j < qlen) dst[j] = c[j] + base;
            sync_lds_only();           // barrier 2

            // prefetch next group's x BEFORE the store burst
            {
                int gn = g + GRID;
                if (gn < nG) {
                    int rown = gn * ROWS + r;
                    v = x[rown < B ? rown : 0];
                }
            }

            // contiguous sweep: group region = 25,472 B = 199 whole 128B lines
            if (rowBase + ROWS <= B) {
                const fx4* src = reinterpret_cast<const fx4*>(lds);
                fx4* d4 = reinterpret_cast<fx4*>(out + (size_t)rowBase * NB);
                fx4 v0 = src[tid];
                fx4 v1 = src[tid + 256];
                fx4 v2 = src[tid + 512];
                fx4 v3 = src[tid + 768];
                fx4 v4 = src[tid + 1024];
                fx4 v5 = src[tid + 1280];
                fx4 v6;
                const bool has7 = tid < (ROWS * NB / 4 - 6 * 256);   // tid < 56
                if (has7) v6 = src[tid + 1536];
                __builtin_nontemporal_store(v0, &d4[tid]);
                __builtin_nontemporal_store(v1, &d4[tid + 256]);
                __builtin_nontemporal_store(v2, &d4[tid + 512]);
                __builtin_nontemporal_store(v3, &d4[tid + 768]);
                __builtin_nontemporal_store(v4, &d4[tid + 1024]);
                __builtin_nontemporal_store(v5, &d4[tid + 1280]);
                if (has7) __builtin_nontemporal_store(v6, &d4[tid + 1536]);
            } else {  // generic tail (unused for B=524288)
                for (int i = tid; i < ROWS * NB; i += NT) {
                    int rr = i / NB;
                    if (rowBase + rr < B)
                        __builtin_nontemporal_store(lds[i], &out[(size_t)rowBase * NB + i]);
                }
            }
        }
    }
}

extern "C" void kernel_launch(void* const* d_in, const int* in_sizes, int n_in,
                              void* d_out, int out_size, void* d_ws, size_t ws_size,
                              hipStream_t stream) {
    const float2* x = (const float2*)d_in[0];
    float* out = (float*)d_out;
    const int B = in_sizes[0] / 2;                  // (B,2) fp32
    gauss_cdf_kernel<<<GRID, NT, 0, stream>>>(x, out, B);
}

// Round 7
// 409.034 us; speedup vs baseline: 1.5841x; 1.5841x over previous
//
#include <hip/hip_runtime.h>
#include <math.h>

// GaussianLayer: per row (B=524288): mu=x[0], sigma=exp(0.5*x[1]);
// pdf over xx=-99..99, cumsum over 199 bins. Output (B,199) fp32 = 417 MB.
//
// ===== FINAL (champion restore after R12 diagnostic) =====
// Session findings (R6..R12):
//  - dur_us = our kernel + ~266 us harness poison fill (1.669 GB @ 6.26 TB/s)
//    + ~40 us dispatch-boundary gap. Only our kernel is controllable.
//  - R12 byte-scaling (REPS=4, counters finally visible): WRITE scales 4x,
//    FETCH ~= 0 (no write-allocate fetch), marginal rate = 6.35 TB/s =
//    the fill's own ceiling, per-pass overhead ~= 0, per-dispatch fixed
//    transient ~= 74 us (counter mode) / ~40 us (timing mode).
//  - => steady-state store rate is ALREADY at the achievable HBM ceiling;
//    compute/LDS/barriers/occupancy non-binding. This is why five disjoint
//    structures (one-shot R6, persistent R8, wavescan R9, interleaved R10,
//    producer/consumer R11) were time-identical (143-175 us kernel-proper).
//  - Remaining excess = start-state: the fill's dirty tail (<=288 MB in
//    L2+L3, disjoint addresses) writes back under our pass-1 allocation
//    pressure (~35-46 us steal), + dispatch-boundary effects. Zero-sum
//    within the timed iteration (deferring the drain moves the cost into
//    the next fill's window); L2-bypass stores corrupt data (R7).
// Conclusion: effective roofline reached; restoring the best-measured
// kernel (408.8 us) unchanged.

#define ROWS 32
#define SEG  25     // bins per segment; 8 segments, last has 24
#define NB   199
#define NT   256

typedef float fx4 __attribute__((ext_vector_type(4)));  // native vec for nt builtin

__global__ __launch_bounds__(NT, 6)
void gauss_cdf_kernel(const float2* __restrict__ x, float* __restrict__ out, int B) {
    __shared__ __align__(16) float lds[ROWS * NB];   // 25,472 B, flat == out layout
    __shared__ float tot[8 * ROWS];                  // per-segment totals [seg][row]

    const int tid = threadIdx.x;
    const int r   = tid & 31;        // row within block
    const int q   = tid >> 5;        // segment index 0..7
    const int rowBase = blockIdx.x * ROWS;
    const int row = rowBase + r;

    float mu = 0.f, coefA = 0.f, inv_norm = 0.f;
    if (row < B) {
        float2 v = x[row];
        mu = v.x;
        float s  = __expf(-0.5f * v.y);        // 1/sigma
        inv_norm = 0.3989422804014327f * s;    // 1/(sigma*sqrt(2pi))
        coefA    = -0.5f * s * s;              // -1/(2 sigma^2)
    }

    const int qs   = q * SEG;
    const int qlen = (q == 7) ? 24 : 25;       // bin 199 doesn't exist
    const float tb = (float)(qs - 99) - mu;

    // segment cumsum in registers (fully unrolled -> static indices)
    float c[SEG];
    float acc = 0.f;
    #pragma unroll
    for (int j = 0; j < SEG; ++j) {
        float t = tb + (float)j;
        acc += inv_norm * __expf(coefA * t * t);
        c[j] = acc;
    }
    tot[q * ROWS + r] = acc;   // q=7's extra bin harmless: tot[7] never read
    __syncthreads();

    // prefix of earlier segments' totals (<=7 LDS reads)
    float base = 0.f;
    #pragma unroll
    for (int k = 0; k < 7; ++k)
        if (k < q) base += tot[k * ROWS + r];

    float* dst = lds + r * NB + qs;
    #pragma unroll
    for (int j = 0; j < SEG; ++j)
        if (j < qlen) dst[j] = c[j] + base;
    __syncthreads();

    // contiguous NONTEMPORAL float4 sweep: block region = 25,472 B,
    // offset blockIdx*25,472 (16B aligned, whole 64B lines per block)
    if (rowBase + ROWS <= B) {
        const fx4* src = reinterpret_cast<const fx4*>(lds);
        fx4* d4 = reinterpret_cast<fx4*>(out + (size_t)rowBase * NB);
        #pragma unroll 2
        for (int i = tid; i < (ROWS * NB) / 4; i += NT)
            __builtin_nontemporal_store(src[i], &d4[i]);
    } else {  // generic tail (unused for B=524288)
        for (int i = tid; i < ROWS * NB; i += NT) {
            int rr = i / NB;
            if (rowBase + rr < B)
                __builtin_nontemporal_store(lds[i], &out[(size_t)rowBase * NB + i]);
        }
    }
}

extern "C" void kernel_launch(void* const* d_in, const int* in_sizes, int n_in,
                              void* d_out, int out_size, void* d_ws, size_t ws_size,
                              hipStream_t stream) {
    const float2* x = (const float2*)d_in[0];
    float* out = (float*)d_out;
    const int B = in_sizes[0] / 2;                  // (B,2) fp32
    const int grid = (B + ROWS - 1) / ROWS;         // 16384 blocks
    gauss_cdf_kernel<<<grid, NT, 0, stream>>>(x, out, B);
}